// Round 7
// baseline (331.232 us; speedup 1.0000x reference)
//
#include <hip/hip_runtime.h>
#include <hip/hip_bf16.h>

typedef __attribute__((ext_vector_type(8))) __bf16 bf16x8;
typedef __attribute__((ext_vector_type(8))) unsigned short u16x8;
typedef __attribute__((ext_vector_type(4))) float f32x4;

#define MFMA_BF16(a,b,c) __builtin_amdgcn_mfma_f32_16x16x32_bf16((a),(b),(c),0,0,0)

#define ASCALE 0.125f
#define SEQT 512
#define NB 32
#define BT 16384  // NB*SEQT

#define GLD_LDS16(g, l) __builtin_amdgcn_global_load_lds( \
    (__attribute__((address_space(1))) void*)(g), \
    (__attribute__((address_space(3))) void*)(l), 16, 0, 0)

__device__ __forceinline__ unsigned short f2bf(float f) {
    unsigned int u = __float_as_uint(f);
    u += 0x7fffu + ((u >> 16) & 1u);
    return (unsigned short)(u >> 16);
}
__device__ __forceinline__ float bf2f(unsigned short h) {
    return __uint_as_float(((unsigned int)h) << 16);
}

// ---------- cast x (fp32 -> bf16) ----------
__global__ __launch_bounds__(256) void cast_x_kernel(const float* __restrict__ x,
                                                     unsigned short* __restrict__ xb, int n) {
    int i = (blockIdx.x * 256 + threadIdx.x) * 4;
    if (i < n) {
        float4 v = *(const float4*)(x + i);
        ushort4 o;
        o.x = f2bf(v.x); o.y = f2bf(v.y); o.z = f2bf(v.z); o.w = f2bf(v.w);
        *(ushort4*)(xb + i) = o;
    }
}

// ---------- fused weight transpose+cast + bias concat ----------
struct WPack {
    const float* src[9];
    unsigned short* dst[9];
    int K[9];
    const float* bsrc[5];
    float* bdst;
    unsigned short* w1cat;
};

__global__ __launch_bounds__(256) void wconv_all(WPack p) {
    const int z = blockIdx.z;
    const int tid = threadIdx.x;
    if (z == 9) {
        int idx = blockIdx.y * 8 + blockIdx.x;
        if (idx < 5) p.bdst[idx * 256 + tid] = p.bsrc[idx][tid];
        return;
    }
    const int K = p.K[z];
    const int k0 = blockIdx.x * 64;
    if (k0 >= K) return;
    const int n0 = blockIdx.y * 64;
    const int tx = tid & 63, ty = tid >> 6;
    const float* src = p.src[z];
    unsigned short* dst = p.dst[z];
    if (z == 6) {  // straight cast (goS), row-major K x 256
        #pragma unroll
        for (int i = 0; i < 16; ++i) {
            int r = ty * 16 + i;
            dst[(size_t)(k0 + r) * 256 + n0 + tx] = f2bf(src[(size_t)(k0 + r) * 256 + n0 + tx]);
        }
        return;
    }
    __shared__ float tile[64][65];
    #pragma unroll
    for (int i = 0; i < 16; ++i) {
        int r = ty * 16 + i;
        tile[r][tx] = src[(size_t)(k0 + r) * 256 + n0 + tx];
    }
    __syncthreads();
    #pragma unroll
    for (int i = 0; i < 16; ++i) {
        int r = ty * 16 + i;
        unsigned short v = f2bf(tile[tx][r]);
        dst[(size_t)(n0 + r) * K + k0 + tx] = v;
        if (z == 7 && k0 >= 256)
            p.w1cat[(size_t)(n0 + r) * 512 + k0 + tx] = v;
    }
}

// ---------- fused f1 bias: f1b' = f1_b + go_b @ f1_w[:256,:] ----------
__global__ __launch_bounds__(256)
void bias2_k(const float* __restrict__ f1_b, const float* __restrict__ go_b,
             const float* __restrict__ f1_w, float* __restrict__ f1bp) {
    int n = threadIdx.x;
    float s = f1_b[n];
    for (int k = 0; k < 256; ++k) s += go_b[k] * f1_w[k * 256 + n];
    f1bp[n] = s;
}

// ---------- GEMM breg: B in registers, A in LDS (whole 64x256 chunk, dbuf across tiles) ----------
// Block = 64-row M-tile x 128-col N-panel, 4 waves each 64x32. ZERO barriers inside K-loop;
// 1 barrier + vmcnt(0) per phase (M-tile x K-chunk). A swizzle: slot ^= row&31 both sides.
// C[m][n] = sum_k A[m][k]*Bt[n][k] + bias(col). mode 0: bf16 out; 1: f32 out (+resid).
template<int KTOT, int M_ITER>
__global__ __launch_bounds__(256)
void gemm_breg(const unsigned short* __restrict__ A, int lda,
               const unsigned short* __restrict__ Bt, int ldb,
               const float* __restrict__ bias,
               void* __restrict__ out, int ldc, int mode, int do_relu,
               const float* __restrict__ resid) {
    constexpr int NCH = KTOT / 256;     // A chunks per M-tile
    constexpr int NPH = M_ITER * NCH;   // total phases
    constexpr int NFR = KTOT / 32;      // B frags per col-pair slot
    __shared__ __align__(16) unsigned short As[2][64 * 256];
    const int tid = threadIdx.x;
    const int w = tid >> 6, l = tid & 63, g = l >> 4, rl = l & 15;
    const int n0 = blockIdx.y * 128 + w * 32;
    const int mbase = blockIdx.x * (M_ITER * 64);

    // B fragments -> registers (static indexing, fully unrolled)
    bf16x8 breg[2][NFR];
    #pragma unroll
    for (int n = 0; n < 2; ++n) {
        const unsigned short* bp = Bt + (size_t)(n0 + n * 16 + rl) * ldb + g * 8;
        #pragma unroll
        for (int kt = 0; kt < NFR; ++kt)
            breg[n][kt] = *(const bf16x8*)(bp + kt * 32);
    }

#define STAGE_A(P) { \
        const int mt_ = (P) / NCH, ch_ = (P) % NCH; \
        const unsigned short* src_ = A + (size_t)(mbase + mt_ * 64) * lda + ch_ * 256; \
        _Pragma("unroll") \
        for (int j = 0; j < 8; ++j) { \
            int e_ = j * 256 + tid; \
            int r_ = e_ >> 5, sp_ = e_ & 31; \
            GLD_LDS16(src_ + (size_t)r_ * lda + ((sp_ ^ (r_ & 31)) * 8), &As[(P) & 1][e_ * 8]); \
        } }

    STAGE_A(0);
    asm volatile("s_waitcnt vmcnt(0)" ::: "memory");
    __builtin_amdgcn_s_barrier();

    f32x4 acc[4][2];
    #pragma unroll
    for (int p = 0; p < NPH; ++p) {
        if (p % NCH == 0) {
            #pragma unroll
            for (int m = 0; m < 4; ++m)
                #pragma unroll
                for (int n = 0; n < 2; ++n) acc[m][n] = (f32x4){0.f, 0.f, 0.f, 0.f};
        }
        if (p + 1 < NPH) STAGE_A(p + 1);          // prefetch next phase (other buffer)
        const int buf = p & 1, ch = p % NCH;
        #pragma unroll
        for (int kt = 0; kt < 8; ++kt) {
            bf16x8 af[4];
            #pragma unroll
            for (int m = 0; m < 4; ++m) {
                int row = m * 16 + rl;
                af[m] = *(const bf16x8*)&As[buf][row * 256 + (((kt * 4 + g) ^ (row & 31)) * 8)];
            }
            #pragma unroll
            for (int m = 0; m < 4; ++m)
                #pragma unroll
                for (int n = 0; n < 2; ++n)
                    acc[m][n] = MFMA_BF16(af[m], breg[n][ch * 8 + kt], acc[m][n]);
        }
        if (p % NCH == NCH - 1) {
            const int mrow = mbase + (p / NCH) * 64;
            #pragma unroll
            for (int m = 0; m < 4; ++m) {
                #pragma unroll
                for (int n = 0; n < 2; ++n) {
                    #pragma unroll
                    for (int r = 0; r < 4; ++r) {
                        int row = mrow + m * 16 + g * 4 + r;
                        int col = n0 + n * 16 + rl;
                        float v = acc[m][n][r] + (bias ? bias[col] : 0.f);
                        if (do_relu) v = fmaxf(v, 0.f);
                        if (mode == 0) {
                            ((unsigned short*)out)[(size_t)row * ldc + col] = f2bf(v);
                        } else {
                            float res = resid ? resid[(size_t)row * ldc + col] : 0.f;
                            ((float*)out)[(size_t)row * ldc + col] = v + res;
                        }
                    }
                }
            }
        }
        asm volatile("s_waitcnt vmcnt(0)" ::: "memory");
        __builtin_amdgcn_s_barrier();
    }
#undef STAGE_A
}

// ---------- GEMM v5 (kept for vT: row-bias + big-N shape) ----------
template<int BM>
__global__ __launch_bounds__(256)
void gemm_v5(const unsigned short* __restrict__ A, int lda,
             const unsigned short* __restrict__ Bt, int ldb,
             const float* __restrict__ bias, int K,
             void* __restrict__ out, int ldc, int mode, int do_relu, int bias_row,
             const float* __restrict__ resid) {
    constexpr int BN = 128;
    constexpr int AR = BM / 64, BR = BN / 64;
    constexpr int MFM = BM / 32, MFN = 4;
    __shared__ __align__(16) unsigned short As[2][BM * 32];
    __shared__ __align__(16) unsigned short Bs[2][BN * 32];
    const int tid = threadIdx.x;
    const int w = tid >> 6, l = tid & 63, g = l >> 4, rl = l & 15;
    const int wrow = (w >> 1) * (BM / 2);
    const int wcol = (w & 1) * 64;
    const int m0 = blockIdx.x * BM, n0 = blockIdx.y * BN;

    f32x4 acc[MFM][MFN];
    #pragma unroll
    for (int m = 0; m < MFM; ++m)
        #pragma unroll
        for (int n = 0; n < MFN; ++n) acc[m][n] = (f32x4){0.f, 0.f, 0.f, 0.f};

    auto stage = [&](int buf, int k0) {
        #pragma unroll
        for (int j = 0; j < AR; ++j) {
            int e = j * 256 + tid;
            GLD_LDS16(A + (size_t)(m0 + (e >> 2)) * lda + k0 + (e & 3) * 8, &As[buf][e * 8]);
        }
        #pragma unroll
        for (int j = 0; j < BR; ++j) {
            int e = j * 256 + tid;
            GLD_LDS16(Bt + (size_t)(n0 + (e >> 2)) * ldb + k0 + (e & 3) * 8, &Bs[buf][e * 8]);
        }
    };

    const int NIT = K >> 5;
    stage(0, 0);
    for (int it = 0; it < NIT; ++it) {
        const int cur = it & 1;
        if (it + 1 < NIT) {
            stage(cur ^ 1, (it + 1) << 5);
            asm volatile("s_waitcnt vmcnt(%0)" :: "n"(AR + BR) : "memory");
        } else {
            asm volatile("s_waitcnt vmcnt(0)" ::: "memory");
        }
        __builtin_amdgcn_s_barrier();
        bf16x8 af[MFM], bf_[MFN];
        #pragma unroll
        for (int m = 0; m < MFM; ++m)
            af[m] = *(const bf16x8*)&As[cur][(wrow + m * 16 + rl) * 32 + g * 8];
        #pragma unroll
        for (int n = 0; n < MFN; ++n)
            bf_[n] = *(const bf16x8*)&Bs[cur][(wcol + n * 16 + rl) * 32 + g * 8];
        #pragma unroll
        for (int m = 0; m < MFM; ++m)
            #pragma unroll
            for (int n = 0; n < MFN; ++n)
                acc[m][n] = MFMA_BF16(af[m], bf_[n], acc[m][n]);
        __builtin_amdgcn_s_barrier();
    }

    #pragma unroll
    for (int m = 0; m < MFM; ++m) {
        #pragma unroll
        for (int n = 0; n < MFN; ++n) {
            #pragma unroll
            for (int r = 0; r < 4; ++r) {
                int row = m0 + wrow + m * 16 + g * 4 + r;
                int col = n0 + wcol + n * 16 + rl;
                float bv = bias ? (bias_row ? bias[row] : bias[col]) : 0.f;
                float v = acc[m][n][r] + bv;
                if (do_relu) v = fmaxf(v, 0.f);
                if (mode == 0) {
                    ((unsigned short*)out)[(size_t)row * ldc + col] = f2bf(v);
                } else {
                    float res = resid ? resid[(size_t)row * ldc + col] : 0.f;
                    ((float*)out)[(size_t)row * ldc + col] = v + res;
                }
            }
        }
    }
}

// ---------- global attention: no online-max (logits bounded), V pre-transposed ----------
__global__ __launch_bounds__(256)
void attn_global2(const unsigned short* __restrict__ proj, const unsigned short* __restrict__ vT,
                  const float* __restrict__ rpb, unsigned short* __restrict__ gout, int ostride) {
    __shared__ __align__(16) unsigned short Ks[64][72];
    __shared__ __align__(16) unsigned short Vs[64][72];
    __shared__ __align__(16) unsigned short Ps[64][72];
    __shared__ float rb_s[127];

    const int tid = threadIdx.x;
    const int w = tid >> 6, l = tid & 63, g = l >> 4, rl = l & 15;
    const int bh = blockIdx.y, b = bh >> 2, h = bh & 3;
    const int t0 = blockIdx.x * 64;

    bf16x8 qf[2];
    #pragma unroll
    for (int kk = 0; kk < 2; ++kk)
        qf[kk] = *(const bf16x8*)(proj + (size_t)(b * SEQT + t0 + w * 16 + rl) * 1280
                                  + h * 64 + kk * 32 + g * 8);

    f32x4 oacc[4];
    #pragma unroll
    for (int n = 0; n < 4; ++n) oacc[n] = (f32x4){0.f, 0.f, 0.f, 0.f};
    float lpart[4] = {0.f, 0.f, 0.f, 0.f};

    for (int s0 = 0; s0 < SEQT; s0 += 64) {
        __syncthreads();
        #pragma unroll
        for (int cc = 0; cc < 2; ++cc) {
            int c = tid + cc * 256;
            int sr = c >> 3, hc = c & 7;
            u16x8 kv = *(const u16x8*)(proj + (size_t)(b * SEQT + s0 + sr) * 1280
                                       + 256 + h * 64 + hc * 8);
            *(u16x8*)&Ks[sr][hc * 8] = kv;
            u16x8 vv = *(const u16x8*)(vT + (size_t)(h * 64 + sr) * BT
                                       + b * SEQT + s0 + hc * 8);
            *(u16x8*)&Vs[sr][hc * 8] = vv;
        }
        if (tid < 127) {
            int dd = s0 - t0 + 448 + tid;
            rb_s[tid] = rpb[dd * 4 + h];
        }
        __syncthreads();

        f32x4 sacc[4];
        #pragma unroll
        for (int n = 0; n < 4; ++n) sacc[n] = (f32x4){0.f, 0.f, 0.f, 0.f};
        #pragma unroll
        for (int kk = 0; kk < 2; ++kk) {
            #pragma unroll
            for (int n = 0; n < 4; ++n) {
                bf16x8 kf = *(const bf16x8*)&Ks[n * 16 + rl][kk * 32 + g * 8];
                sacc[n] = MFMA_BF16(qf[kk], kf, sacc[n]);
            }
        }

        #pragma unroll
        for (int n = 0; n < 4; ++n) {
            #pragma unroll
            for (int r = 0; r < 4; ++r) {
                int relc = (n * 16 + rl) - (w * 16 + g * 4 + r) + 63;
                float p = __expf(sacc[n][r] * ASCALE + rb_s[relc]);
                lpart[r] += p;
                Ps[w * 16 + g * 4 + r][n * 16 + rl] = f2bf(p);
            }
        }

        #pragma unroll
        for (int kk = 0; kk < 2; ++kk) {
            bf16x8 pf = *(const bf16x8*)&Ps[w * 16 + rl][kk * 32 + g * 8];
            #pragma unroll
            for (int n = 0; n < 4; ++n) {
                bf16x8 vf = *(const bf16x8*)&Vs[n * 16 + rl][kk * 32 + g * 8];
                oacc[n] = MFMA_BF16(pf, vf, oacc[n]);
            }
        }
    }

    #pragma unroll
    for (int r = 0; r < 4; ++r) {
        #pragma unroll
        for (int mk = 1; mk < 16; mk <<= 1) lpart[r] += __shfl_xor(lpart[r], mk);
    }
    #pragma unroll
    for (int n = 0; n < 4; ++n) {
        #pragma unroll
        for (int r = 0; r < 4; ++r) {
            float o = oacc[n][r] / lpart[r];
            gout[(size_t)(b * SEQT + t0 + w * 16 + g * 4 + r) * ostride
                 + h * 64 + n * 16 + rl] = f2bf(o);
        }
    }
}

// ---------- local windowed attention ----------
__global__ __launch_bounds__(256)
void local_attn(const unsigned short* __restrict__ proj,
                const float* __restrict__ lk_bias, const float* __restrict__ lv_bias,
                unsigned short* __restrict__ fused) {
    const int tid = threadIdx.x;
    const int wv = tid >> 6, lane = tid & 63;
    const int row = blockIdx.x * 4 + wv;
    const int b = row >> 9, tt = row & 511;

    ushort4 qv = *((const ushort4*)(proj + (size_t)row * 1280 + 512) + lane);
    float qf[4] = {bf2f(qv.x), bf2f(qv.y), bf2f(qv.z), bf2f(qv.w)};

    float sw[10];
    #pragma unroll
    for (int w = 0; w < 10; ++w) {
        int src = tt + w - 5;
        float kf[4];
        if (src >= 0 && src < 512) {
            ushort4 kv = *((const ushort4*)(proj + (size_t)(b * 512 + src) * 1280 + 768) + lane);
            kf[0] = bf2f(kv.x); kf[1] = bf2f(kv.y); kf[2] = bf2f(kv.z); kf[3] = bf2f(kv.w);
        } else {
            float4 kb4 = *((const float4*)lk_bias + lane);
            kf[0] = kb4.x; kf[1] = kb4.y; kf[2] = kb4.z; kf[3] = kb4.w;
        }
        float p = qf[0] * kf[0] + qf[1] * kf[1] + qf[2] * kf[2] + qf[3] * kf[3];
        #pragma unroll
        for (int mk = 1; mk < 64; mk <<= 1) p += __shfl_xor(p, mk);
        sw[w] = p * ASCALE;
    }
    float mx = sw[0];
    #pragma unroll
    for (int w = 1; w < 10; ++w) mx = fmaxf(mx, sw[w]);
    float pv[10], s = 0.f;
    #pragma unroll
    for (int w = 0; w < 10; ++w) { pv[w] = __expf(sw[w] - mx); s += pv[w]; }
    float inv = 1.f / s;

    float of[4] = {0.f, 0.f, 0.f, 0.f};
    #pragma unroll
    for (int w = 0; w < 10; ++w) {
        int src = tt + w - 5;
        float vf[4];
        if (src >= 0 && src < 512) {
            ushort4 vv = *((const ushort4*)(proj + (size_t)(b * 512 + src) * 1280 + 1024) + lane);
            vf[0] = bf2f(vv.x); vf[1] = bf2f(vv.y); vf[2] = bf2f(vv.z); vf[3] = bf2f(vv.w);
        } else {
            float4 vb4 = *((const float4*)lv_bias + lane);
            vf[0] = vb4.x; vf[1] = vb4.y; vf[2] = vb4.z; vf[3] = vb4.w;
        }
        float pw = pv[w] * inv;
        of[0] += pw * vf[0]; of[1] += pw * vf[1]; of[2] += pw * vf[2]; of[3] += pw * vf[3];
    }
    ushort4 o;
    o.x = f2bf(of[0]); o.y = f2bf(of[1]); o.z = f2bf(of[2]); o.w = f2bf(of[3]);
    *((ushort4*)(fused + (size_t)row * 512 + 256) + lane) = o;
}

// ---------- pooled mean partials ----------
__global__ __launch_bounds__(256)
void pooled_part(const unsigned short* __restrict__ xb, float* __restrict__ pp) {
    int b = blockIdx.x >> 3, tc = blockIdx.x & 7;
    int d = threadIdx.x;
    const unsigned short* xp = xb + ((size_t)b * SEQT + tc * 64) * 256 + d;
    float s = 0.f;
    #pragma unroll 8
    for (int t = 0; t < 64; ++t) s += bf2f(xp[(size_t)t * 256]);
    pp[(size_t)(tc * 32 + b) * 256 + d] = s * (1.0f / 512.0f);
}

// ---------- pattern scores ----------
__global__ __launch_bounds__(256)
void pattern_k(const float* __restrict__ pp, const float* __restrict__ pe,
               const float* __restrict__ pq_w, const float* __restrict__ pq_b,
               const float* __restrict__ pk_w, const float* __restrict__ pk_b,
               float* __restrict__ out_scores) {
    __shared__ float pool_s[256];
    __shared__ float pes[3 * 256];
    __shared__ float pq_s[256];
    __shared__ float pk_s[3][256];
    __shared__ float pw_s[4][3];
    int b = blockIdx.x, d = threadIdx.x;
    float ps = 0.f;
    #pragma unroll
    for (int tc = 0; tc < 8; ++tc) ps += pp[(size_t)(tc * 32 + b) * 256 + d];
    pool_s[d] = ps;
    pes[d] = pe[d]; pes[256 + d] = pe[256 + d]; pes[512 + d] = pe[512 + d];
    __syncthreads();
    float acc = pq_b[d];
    for (int k = 0; k < 256; ++k) acc += pool_s[k] * pq_w[k * 256 + d];
    pq_s[d] = acc;
    for (int j = 0; j < 3; ++j) {
        float a = pk_b[d];
        for (int k = 0; k < 256; ++k) a += pes[j * 256 + k] * pk_w[k * 256 + d];
        pk_s[j][d] = a;
    }
    __syncthreads();
    int h = d >> 6, lane = d & 63;
    float lg[3];
    #pragma unroll
    for (int j = 0; j < 3; ++j) {
        float p = pq_s[h * 64 + lane] * pk_s[j][h * 64 + lane];
        #pragma unroll
        for (int mk = 1; mk < 64; mk <<= 1) p += __shfl_xor(p, mk);
        lg[j] = p * ASCALE;
    }
    float mx = fmaxf(fmaxf(lg[0], lg[1]), lg[2]);
    float e0 = __expf(lg[0] - mx), e1 = __expf(lg[1] - mx), e2 = __expf(lg[2] - mx);
    float sinv = 1.f / (e0 + e1 + e2);
    if (lane == 0) { pw_s[h][0] = e0 * sinv; pw_s[h][1] = e1 * sinv; pw_s[h][2] = e2 * sinv; }
    __syncthreads();
    if (d < 3)
        out_scores[b * 3 + d] = 0.25f * (pw_s[0][d] + pw_s[1][d] + pw_s[2][d] + pw_s[3][d]);
}

extern "C" void kernel_launch(void* const* d_in, const int* in_sizes, int n_in,
                              void* d_out, int out_size, void* d_ws, size_t ws_size,
                              hipStream_t stream) {
    (void)in_sizes; (void)n_in; (void)out_size; (void)ws_size;
    const float* x    = (const float*)d_in[0];
    const float* gq_w = (const float*)d_in[1];  const float* gq_b = (const float*)d_in[2];
    const float* gk_w = (const float*)d_in[3];  const float* gk_b = (const float*)d_in[4];
    const float* gv_w = (const float*)d_in[5];  const float* gv_b = (const float*)d_in[6];
    const float* go_w = (const float*)d_in[7];  const float* go_b = (const float*)d_in[8];
    const float* rpb  = (const float*)d_in[9];
    const float* lq_w = (const float*)d_in[10]; const float* lq_b = (const float*)d_in[11];
    const float* lk_w = (const float*)d_in[12]; const float* lk_b = (const float*)d_in[13];
    const float* lv_w = (const float*)d_in[14]; const float* lv_b = (const float*)d_in[15];
    const float* pe   = (const float*)d_in[16];
    const float* pq_w = (const float*)d_in[17]; const float* pq_b = (const float*)d_in[18];
    const float* pk_w = (const float*)d_in[19]; const float* pk_b = (const float*)d_in[20];
    const float* f1_w = (const float*)d_in[21]; const float* f1_b = (const float*)d_in[22];
    const float* f2_w = (const float*)d_in[23]; const float* f2_b = (const float*)d_in[24];

    char* ws = (char*)d_ws;
    const size_t MB = 1024 * 1024;
    unsigned short* xb    = (unsigned short*)(ws + 0);        // [16384][256]
    unsigned short* proj  = (unsigned short*)(ws + 8 * MB);   // [16384][1280]
    unsigned short* vT    = (unsigned short*)(ws + 48 * MB);  // [256][16384]
    unsigned short* fused = (unsigned short*)(ws + 56 * MB);  // [16384][512] = [g_out | local]
    unsigned short* hb    = (unsigned short*)(ws + 72 * MB);  // [16384][256]
    unsigned short* wts   = (unsigned short*)(ws + 80 * MB);
    unsigned short* gv_t  = wts;                  // [256][256]
    unsigned short* goS   = gv_t + 65536;         // [256][256] straight cast of go_w
    unsigned short* f1_t  = goS + 65536;          // [256][512]
    unsigned short* f2_t  = f1_t + 131072;        // [256][256]
    unsigned short* wcat  = f2_t + 65536;         // [1280][256]
    unsigned short* w1cat = wcat + 327680;        // [256][512] fused (go.f1A | f1B) weight
    float* bcat = (float*)(ws + 82 * MB);         // [1280]
    float* f1bp = bcat + 2048;                    // [256]
    float* pp   = (float*)(ws + 83 * MB);         // [8*32][256] partials

    float* out = (float*)d_out;
    float* out_scores = out + (size_t)BT * 256;

    // 1. casts, weight transposes, fused biases
    cast_x_kernel<<<4096, 256, 0, stream>>>(x, xb, BT * 256);
    WPack p;
    p.src[0] = gq_w; p.dst[0] = wcat + 0 * 65536; p.K[0] = 256;
    p.src[1] = gk_w; p.dst[1] = wcat + 1 * 65536; p.K[1] = 256;
    p.src[2] = lq_w; p.dst[2] = wcat + 2 * 65536; p.K[2] = 256;
    p.src[3] = lk_w; p.dst[3] = wcat + 3 * 65536; p.K[3] = 256;
    p.src[4] = lv_w; p.dst[4] = wcat + 4 * 65536; p.K[4] = 256;
    p.src[5] = gv_w; p.dst[5] = gv_t;  p.K[5] = 256;
    p.src[6] = go_w; p.dst[6] = goS;   p.K[6] = 256;   // straight
    p.src[7] = f1_w; p.dst[7] = f1_t;  p.K[7] = 512;   // + mirrors K>=256 half into w1cat
    p.src[8] = f2_w; p.dst[8] = f2_t;  p.K[8] = 256;
    p.bsrc[0] = gq_b; p.bsrc[1] = gk_b; p.bsrc[2] = lq_b; p.bsrc[3] = lk_b; p.bsrc[4] = lv_b;
    p.bdst = bcat;
    p.w1cat = w1cat;
    wconv_all<<<dim3(8, 4, 10), 256, 0, stream>>>(p);
    bias2_k<<<1, 256, 0, stream>>>(f1_b, go_b, f1_w, f1bp);
    pooled_part<<<256, 256, 0, stream>>>(xb, pp);

    // 1b. W1 = f1A^T @ go_w^T  -> w1cat[:, 0:256]
    gemm_breg<256, 1><<<dim3(4, 2), 256, 0, stream>>>(f1_t, 512, goS, 256, nullptr,
                                                      w1cat, 512, 0, 0, nullptr);

    // 2. fused projection GEMM (q|k|lq|lk|lv) + V^T projection
    gemm_breg<256, 4><<<dim3(64, 10), 256, 0, stream>>>(xb, 256, wcat, 256, bcat,
                                                        proj, 1280, 0, 0, nullptr);
    gemm_v5<64><<<dim3(4, BT / 128), 256, 0, stream>>>(gv_t, 256, xb, 256, gv_b, 256,
                                                       vT, BT, 0, 0, 1, nullptr);

    // 3. global attention -> fused[:, 0:256] (raw g_out; go folded into W1)
    attn_global2<<<dim3(SEQT / 64, NB * 4), 256, 0, stream>>>(proj, vT, rpb, fused, 512);

    // 4. local attention -> fused[:, 256:512]
    local_attn<<<BT / 4, 256, 0, stream>>>(proj, lk_b, lv_b, fused);

    // 5. FFN (go composed into f1): h = relu(fused @ w1cat^T + f1b')
    gemm_breg<512, 1><<<dim3(256, 2), 256, 0, stream>>>(fused, 512, w1cat, 512, f1bp,
                                                        hb, 256, 0, 1, nullptr);
    gemm_breg<256, 1><<<dim3(256, 2), 256, 0, stream>>>(hb, 256, f2_t, 256, f2_b,
                                                        out, 256, 1, 0, x);

    // 6. pattern path
    pattern_k<<<NB, 256, 0, stream>>>(pp, pe, pq_w, pq_b, pk_w, pk_b, out_scores);
}

// Round 8
// 308.117 us; speedup vs baseline: 1.0750x; 1.0750x over previous
//
#include <hip/hip_runtime.h>
#include <hip/hip_bf16.h>

typedef __attribute__((ext_vector_type(8))) __bf16 bf16x8;
typedef __attribute__((ext_vector_type(8))) unsigned short u16x8;
typedef __attribute__((ext_vector_type(4))) float f32x4;

#define MFMA_BF16(a,b,c) __builtin_amdgcn_mfma_f32_16x16x32_bf16((a),(b),(c),0,0,0)

#define ASCALE 0.125f
#define SEQT 512
#define NB 32
#define BT 16384  // NB*SEQT

#define GLD_LDS16(g, l) __builtin_amdgcn_global_load_lds( \
    (__attribute__((address_space(1))) void*)(g), \
    (__attribute__((address_space(3))) void*)(l), 16, 0, 0)

__device__ __forceinline__ unsigned short f2bf(float f) {
    unsigned int u = __float_as_uint(f);
    u += 0x7fffu + ((u >> 16) & 1u);
    return (unsigned short)(u >> 16);
}
__device__ __forceinline__ float bf2f(unsigned short h) {
    return __uint_as_float(((unsigned int)h) << 16);
}

// ---------- cast x (fp32 -> bf16) ----------
__global__ __launch_bounds__(256) void cast_x_kernel(const float* __restrict__ x,
                                                     unsigned short* __restrict__ xb, int n) {
    int i = (blockIdx.x * 256 + threadIdx.x) * 4;
    if (i < n) {
        float4 v = *(const float4*)(x + i);
        ushort4 o;
        o.x = f2bf(v.x); o.y = f2bf(v.y); o.z = f2bf(v.z); o.w = f2bf(v.w);
        *(ushort4*)(xb + i) = o;
    }
}

// ---------- fused weight transpose+cast + bias concat + fused f1 bias ----------
struct WPack {
    const float* src[9];
    unsigned short* dst[9];
    int K[9];
    const float* bsrc[5];
    float* bdst;
    unsigned short* w1cat;
    const float* f1_b; const float* go_b; const float* f1_w; float* f1bp;
};

__global__ __launch_bounds__(256) void wconv_all(WPack p) {
    const int z = blockIdx.z;
    const int tid = threadIdx.x;
    if (z == 9) {
        int idx = blockIdx.y * 8 + blockIdx.x;
        if (idx < 5) p.bdst[idx * 256 + tid] = p.bsrc[idx][tid];
        return;
    }
    if (z == 10) {  // f1b' = f1_b + go_b @ f1_w[:256,:]
        if (blockIdx.x != 0 || blockIdx.y != 0) return;
        float s = p.f1_b[tid];
        for (int k = 0; k < 256; ++k) s += p.go_b[k] * p.f1_w[k * 256 + tid];
        p.f1bp[tid] = s;
        return;
    }
    const int K = p.K[z];
    const int k0 = blockIdx.x * 64;
    if (k0 >= K) return;
    const int n0 = blockIdx.y * 64;
    const int tx = tid & 63, ty = tid >> 6;
    const float* src = p.src[z];
    unsigned short* dst = p.dst[z];
    if (z == 6) {  // straight cast (goS), row-major K x 256
        #pragma unroll
        for (int i = 0; i < 16; ++i) {
            int r = ty * 16 + i;
            dst[(size_t)(k0 + r) * 256 + n0 + tx] = f2bf(src[(size_t)(k0 + r) * 256 + n0 + tx]);
        }
        return;
    }
    __shared__ float tile[64][65];
    #pragma unroll
    for (int i = 0; i < 16; ++i) {
        int r = ty * 16 + i;
        tile[r][tx] = src[(size_t)(k0 + r) * 256 + n0 + tx];
    }
    __syncthreads();
    #pragma unroll
    for (int i = 0; i < 16; ++i) {
        int r = ty * 16 + i;
        unsigned short v = f2bf(tile[tx][r]);
        dst[(size_t)(n0 + r) * K + k0 + tx] = v;
        if (z == 7 && k0 >= 256)
            p.w1cat[(size_t)(n0 + r) * 512 + k0 + tx] = v;
    }
}

// ---------- GEMM tb: BMx128 tile, TRIPLE-buffered, depth-2 prefetch, 1 barrier/iter ----------
// C[m][n] = sum_k A[m][k]*Bt[n][k] + bias. mode 0: bf16 out; 1: f32 out (+resid).
// Per iter: vmcnt(R)->barrier->stage(it+2)->ds_read+MFMA. stage(it+2) hits buffer (it-1)%3,
// safe because the barrier is only passed after all waves finished iter it-1's reads.
template<int BM, int KT>
__global__ __launch_bounds__(256)
void gemm_tb(const unsigned short* __restrict__ A, int lda,
             const unsigned short* __restrict__ Bt, int ldb,
             const float* __restrict__ bias,
             void* __restrict__ out, int ldc, int mode, int do_relu, int bias_row,
             const float* __restrict__ resid) {
    constexpr int BN = 128;
    constexpr int ALD = BM / 64;          // A global_load_lds per thread per stage
    constexpr int BLD = BN / 64;          // B loads per thread per stage
    constexpr int R = ALD + BLD;          // loads in flight per stage
    constexpr int NIT = KT / 32;
    constexpr int MFM = BM / 32, MFN = 4;
    __shared__ __align__(16) unsigned short As[3][BM * 32];
    __shared__ __align__(16) unsigned short Bs[3][BN * 32];
    const int tid = threadIdx.x;
    const int w = tid >> 6, l = tid & 63, g = l >> 4, rl = l & 15;
    const int wrow = (w >> 1) * (BM / 2);
    const int wcol = (w & 1) * 64;
    const int m0 = blockIdx.x * BM, n0 = blockIdx.y * BN;

    f32x4 acc[MFM][MFN];
    #pragma unroll
    for (int m = 0; m < MFM; ++m)
        #pragma unroll
        for (int n = 0; n < MFN; ++n) acc[m][n] = (f32x4){0.f, 0.f, 0.f, 0.f};

    auto stage = [&](int buf, int k0) {
        #pragma unroll
        for (int j = 0; j < ALD; ++j) {
            int e = j * 256 + tid;
            GLD_LDS16(A + (size_t)(m0 + (e >> 2)) * lda + k0 + (e & 3) * 8, &As[buf][e * 8]);
        }
        #pragma unroll
        for (int j = 0; j < BLD; ++j) {
            int e = j * 256 + tid;
            GLD_LDS16(Bt + (size_t)(n0 + (e >> 2)) * ldb + k0 + (e & 3) * 8, &Bs[buf][e * 8]);
        }
    };

    stage(0, 0);
    stage(1, 32);
    #pragma unroll
    for (int it = 0; it < NIT; ++it) {
        if (it + 1 < NIT) {
            asm volatile("s_waitcnt vmcnt(%0)" :: "n"(R) : "memory");
        } else {
            asm volatile("s_waitcnt vmcnt(0)" ::: "memory");
        }
        __builtin_amdgcn_s_barrier();
        if (it + 2 < NIT) stage((it + 2) % 3, (it + 2) * 32);
        const int cur = it % 3;
        bf16x8 af[MFM], bf_[MFN];
        #pragma unroll
        for (int m = 0; m < MFM; ++m)
            af[m] = *(const bf16x8*)&As[cur][(wrow + m * 16 + rl) * 32 + g * 8];
        #pragma unroll
        for (int n = 0; n < MFN; ++n)
            bf_[n] = *(const bf16x8*)&Bs[cur][(wcol + n * 16 + rl) * 32 + g * 8];
        #pragma unroll
        for (int m = 0; m < MFM; ++m)
            #pragma unroll
            for (int n = 0; n < MFN; ++n)
                acc[m][n] = MFMA_BF16(af[m], bf_[n], acc[m][n]);
    }

    #pragma unroll
    for (int m = 0; m < MFM; ++m) {
        #pragma unroll
        for (int n = 0; n < MFN; ++n) {
            #pragma unroll
            for (int r = 0; r < 4; ++r) {
                int row = m0 + wrow + m * 16 + g * 4 + r;
                int col = n0 + wcol + n * 16 + rl;
                float bv = bias ? (bias_row ? bias[row] : bias[col]) : 0.f;
                float v = acc[m][n][r] + bv;
                if (do_relu) v = fmaxf(v, 0.f);
                if (mode == 0) {
                    ((unsigned short*)out)[(size_t)row * ldc + col] = f2bf(v);
                } else {
                    float res = resid ? resid[(size_t)row * ldc + col] : 0.f;
                    ((float*)out)[(size_t)row * ldc + col] = v + res;
                }
            }
        }
    }
}

// ---------- global attention: no online-max (logits bounded), V pre-transposed ----------
__global__ __launch_bounds__(256)
void attn_global2(const unsigned short* __restrict__ proj, const unsigned short* __restrict__ vT,
                  const float* __restrict__ rpb, unsigned short* __restrict__ gout, int ostride) {
    __shared__ __align__(16) unsigned short Ks[64][72];
    __shared__ __align__(16) unsigned short Vs[64][72];
    __shared__ __align__(16) unsigned short Ps[64][72];
    __shared__ float rb_s[127];

    const int tid = threadIdx.x;
    const int w = tid >> 6, l = tid & 63, g = l >> 4, rl = l & 15;
    const int bh = blockIdx.y, b = bh >> 2, h = bh & 3;
    const int t0 = blockIdx.x * 64;

    bf16x8 qf[2];
    #pragma unroll
    for (int kk = 0; kk < 2; ++kk)
        qf[kk] = *(const bf16x8*)(proj + (size_t)(b * SEQT + t0 + w * 16 + rl) * 1280
                                  + h * 64 + kk * 32 + g * 8);

    f32x4 oacc[4];
    #pragma unroll
    for (int n = 0; n < 4; ++n) oacc[n] = (f32x4){0.f, 0.f, 0.f, 0.f};
    float lpart[4] = {0.f, 0.f, 0.f, 0.f};

    for (int s0 = 0; s0 < SEQT; s0 += 64) {
        __syncthreads();
        #pragma unroll
        for (int cc = 0; cc < 2; ++cc) {
            int c = tid + cc * 256;
            int sr = c >> 3, hc = c & 7;
            u16x8 kv = *(const u16x8*)(proj + (size_t)(b * SEQT + s0 + sr) * 1280
                                       + 256 + h * 64 + hc * 8);
            *(u16x8*)&Ks[sr][hc * 8] = kv;
            u16x8 vv = *(const u16x8*)(vT + (size_t)(h * 64 + sr) * BT
                                       + b * SEQT + s0 + hc * 8);
            *(u16x8*)&Vs[sr][hc * 8] = vv;
        }
        if (tid < 127) {
            int dd = s0 - t0 + 448 + tid;
            rb_s[tid] = rpb[dd * 4 + h];
        }
        __syncthreads();

        f32x4 sacc[4];
        #pragma unroll
        for (int n = 0; n < 4; ++n) sacc[n] = (f32x4){0.f, 0.f, 0.f, 0.f};
        #pragma unroll
        for (int kk = 0; kk < 2; ++kk) {
            #pragma unroll
            for (int n = 0; n < 4; ++n) {
                bf16x8 kf = *(const bf16x8*)&Ks[n * 16 + rl][kk * 32 + g * 8];
                sacc[n] = MFMA_BF16(qf[kk], kf, sacc[n]);
            }
        }

        #pragma unroll
        for (int n = 0; n < 4; ++n) {
            #pragma unroll
            for (int r = 0; r < 4; ++r) {
                int relc = (n * 16 + rl) - (w * 16 + g * 4 + r) + 63;
                float p = __expf(sacc[n][r] * ASCALE + rb_s[relc]);
                lpart[r] += p;
                Ps[w * 16 + g * 4 + r][n * 16 + rl] = f2bf(p);
            }
        }

        #pragma unroll
        for (int kk = 0; kk < 2; ++kk) {
            bf16x8 pf = *(const bf16x8*)&Ps[w * 16 + rl][kk * 32 + g * 8];
            #pragma unroll
            for (int n = 0; n < 4; ++n) {
                bf16x8 vf = *(const bf16x8*)&Vs[n * 16 + rl][kk * 32 + g * 8];
                oacc[n] = MFMA_BF16(pf, vf, oacc[n]);
            }
        }
    }

    #pragma unroll
    for (int r = 0; r < 4; ++r) {
        #pragma unroll
        for (int mk = 1; mk < 16; mk <<= 1) lpart[r] += __shfl_xor(lpart[r], mk);
    }
    #pragma unroll
    for (int n = 0; n < 4; ++n) {
        #pragma unroll
        for (int r = 0; r < 4; ++r) {
            float o = oacc[n][r] / lpart[r];
            gout[(size_t)(b * SEQT + t0 + w * 16 + g * 4 + r) * ostride
                 + h * 64 + n * 16 + rl] = f2bf(o);
        }
    }
}

// ---------- local windowed attention ----------
__global__ __launch_bounds__(256)
void local_attn(const unsigned short* __restrict__ proj,
                const float* __restrict__ lk_bias, const float* __restrict__ lv_bias,
                unsigned short* __restrict__ fused) {
    const int tid = threadIdx.x;
    const int wv = tid >> 6, lane = tid & 63;
    const int row = blockIdx.x * 4 + wv;
    const int b = row >> 9, tt = row & 511;

    ushort4 qv = *((const ushort4*)(proj + (size_t)row * 1280 + 512) + lane);
    float qf[4] = {bf2f(qv.x), bf2f(qv.y), bf2f(qv.z), bf2f(qv.w)};

    float sw[10];
    #pragma unroll
    for (int w = 0; w < 10; ++w) {
        int src = tt + w - 5;
        float kf[4];
        if (src >= 0 && src < 512) {
            ushort4 kv = *((const ushort4*)(proj + (size_t)(b * 512 + src) * 1280 + 768) + lane);
            kf[0] = bf2f(kv.x); kf[1] = bf2f(kv.y); kf[2] = bf2f(kv.z); kf[3] = bf2f(kv.w);
        } else {
            float4 kb4 = *((const float4*)lk_bias + lane);
            kf[0] = kb4.x; kf[1] = kb4.y; kf[2] = kb4.z; kf[3] = kb4.w;
        }
        float p = qf[0] * kf[0] + qf[1] * kf[1] + qf[2] * kf[2] + qf[3] * kf[3];
        #pragma unroll
        for (int mk = 1; mk < 64; mk <<= 1) p += __shfl_xor(p, mk);
        sw[w] = p * ASCALE;
    }
    float mx = sw[0];
    #pragma unroll
    for (int w = 1; w < 10; ++w) mx = fmaxf(mx, sw[w]);
    float pv[10], s = 0.f;
    #pragma unroll
    for (int w = 0; w < 10; ++w) { pv[w] = __expf(sw[w] - mx); s += pv[w]; }
    float inv = 1.f / s;

    float of[4] = {0.f, 0.f, 0.f, 0.f};
    #pragma unroll
    for (int w = 0; w < 10; ++w) {
        int src = tt + w - 5;
        float vf[4];
        if (src >= 0 && src < 512) {
            ushort4 vv = *((const ushort4*)(proj + (size_t)(b * 512 + src) * 1280 + 1024) + lane);
            vf[0] = bf2f(vv.x); vf[1] = bf2f(vv.y); vf[2] = bf2f(vv.z); vf[3] = bf2f(vv.w);
        } else {
            float4 vb4 = *((const float4*)lv_bias + lane);
            vf[0] = vb4.x; vf[1] = vb4.y; vf[2] = vb4.z; vf[3] = vb4.w;
        }
        float pw = pv[w] * inv;
        of[0] += pw * vf[0]; of[1] += pw * vf[1]; of[2] += pw * vf[2]; of[3] += pw * vf[3];
    }
    ushort4 o;
    o.x = f2bf(of[0]); o.y = f2bf(of[1]); o.z = f2bf(of[2]); o.w = f2bf(of[3]);
    *((ushort4*)(fused + (size_t)row * 512 + 256) + lane) = o;
}

// ---------- pooled mean partials ----------
__global__ __launch_bounds__(256)
void pooled_part(const unsigned short* __restrict__ xb, float* __restrict__ pp) {
    int b = blockIdx.x >> 3, tc = blockIdx.x & 7;
    int d = threadIdx.x;
    const unsigned short* xp = xb + ((size_t)b * SEQT + tc * 64) * 256 + d;
    float s = 0.f;
    #pragma unroll 8
    for (int t = 0; t < 64; ++t) s += bf2f(xp[(size_t)t * 256]);
    pp[(size_t)(tc * 32 + b) * 256 + d] = s * (1.0f / 512.0f);
}

// ---------- pattern scores ----------
__global__ __launch_bounds__(256)
void pattern_k(const float* __restrict__ pp, const float* __restrict__ pe,
               const float* __restrict__ pq_w, const float* __restrict__ pq_b,
               const float* __restrict__ pk_w, const float* __restrict__ pk_b,
               float* __restrict__ out_scores) {
    __shared__ float pool_s[256];
    __shared__ float pes[3 * 256];
    __shared__ float pq_s[256];
    __shared__ float pk_s[3][256];
    __shared__ float pw_s[4][3];
    int b = blockIdx.x, d = threadIdx.x;
    float ps = 0.f;
    #pragma unroll
    for (int tc = 0; tc < 8; ++tc) ps += pp[(size_t)(tc * 32 + b) * 256 + d];
    pool_s[d] = ps;
    pes[d] = pe[d]; pes[256 + d] = pe[256 + d]; pes[512 + d] = pe[512 + d];
    __syncthreads();
    float acc = pq_b[d];
    for (int k = 0; k < 256; ++k) acc += pool_s[k] * pq_w[k * 256 + d];
    pq_s[d] = acc;
    for (int j = 0; j < 3; ++j) {
        float a = pk_b[d];
        for (int k = 0; k < 256; ++k) a += pes[j * 256 + k] * pk_w[k * 256 + d];
        pk_s[j][d] = a;
    }
    __syncthreads();
    int h = d >> 6, lane = d & 63;
    float lg[3];
    #pragma unroll
    for (int j = 0; j < 3; ++j) {
        float p = pq_s[h * 64 + lane] * pk_s[j][h * 64 + lane];
        #pragma unroll
        for (int mk = 1; mk < 64; mk <<= 1) p += __shfl_xor(p, mk);
        lg[j] = p * ASCALE;
    }
    float mx = fmaxf(fmaxf(lg[0], lg[1]), lg[2]);
    float e0 = __expf(lg[0] - mx), e1 = __expf(lg[1] - mx), e2 = __expf(lg[2] - mx);
    float sinv = 1.f / (e0 + e1 + e2);
    if (lane == 0) { pw_s[h][0] = e0 * sinv; pw_s[h][1] = e1 * sinv; pw_s[h][2] = e2 * sinv; }
    __syncthreads();
    if (d < 3)
        out_scores[b * 3 + d] = 0.25f * (pw_s[0][d] + pw_s[1][d] + pw_s[2][d] + pw_s[3][d]);
}

extern "C" void kernel_launch(void* const* d_in, const int* in_sizes, int n_in,
                              void* d_out, int out_size, void* d_ws, size_t ws_size,
                              hipStream_t stream) {
    (void)in_sizes; (void)n_in; (void)out_size; (void)ws_size;
    const float* x    = (const float*)d_in[0];
    const float* gq_w = (const float*)d_in[1];  const float* gq_b = (const float*)d_in[2];
    const float* gk_w = (const float*)d_in[3];  const float* gk_b = (const float*)d_in[4];
    const float* gv_w = (const float*)d_in[5];  const float* gv_b = (const float*)d_in[6];
    const float* go_w = (const float*)d_in[7];  const float* go_b = (const float*)d_in[8];
    const float* rpb  = (const float*)d_in[9];
    const float* lq_w = (const float*)d_in[10]; const float* lq_b = (const float*)d_in[11];
    const float* lk_w = (const float*)d_in[12]; const float* lk_b = (const float*)d_in[13];
    const float* lv_w = (const float*)d_in[14]; const float* lv_b = (const float*)d_in[15];
    const float* pe   = (const float*)d_in[16];
    const float* pq_w = (const float*)d_in[17]; const float* pq_b = (const float*)d_in[18];
    const float* pk_w = (const float*)d_in[19]; const float* pk_b = (const float*)d_in[20];
    const float* f1_w = (const float*)d_in[21]; const float* f1_b = (const float*)d_in[22];
    const float* f2_w = (const float*)d_in[23]; const float* f2_b = (const float*)d_in[24];

    char* ws = (char*)d_ws;
    const size_t MB = 1024 * 1024;
    unsigned short* xb    = (unsigned short*)(ws + 0);        // [16384][256]
    unsigned short* proj  = (unsigned short*)(ws + 8 * MB);   // [16384][1280]
    unsigned short* vT    = (unsigned short*)(ws + 48 * MB);  // [256][16384]
    unsigned short* fused = (unsigned short*)(ws + 56 * MB);  // [16384][512] = [g_out | local]
    unsigned short* hb    = (unsigned short*)(ws + 72 * MB);  // [16384][256]
    unsigned short* wts   = (unsigned short*)(ws + 80 * MB);
    unsigned short* gv_t  = wts;                  // [256][256]
    unsigned short* goS   = gv_t + 65536;         // [256][256] straight cast of go_w
    unsigned short* f1_t  = goS + 65536;          // [256][512]
    unsigned short* f2_t  = f1_t + 131072;        // [256][256]
    unsigned short* wcat  = f2_t + 65536;         // [1280][256]
    unsigned short* w1cat = wcat + 327680;        // [256][512] fused (go.f1A | f1B) weight
    float* bcat = (float*)(ws + 82 * MB);         // [1280]
    float* f1bp = bcat + 2048;                    // [256]
    float* pp   = (float*)(ws + 83 * MB);         // [8*32][256] partials

    float* out = (float*)d_out;
    float* out_scores = out + (size_t)BT * 256;

    // 1. casts, weight transposes, fused biases (single launch)
    cast_x_kernel<<<4096, 256, 0, stream>>>(x, xb, BT * 256);
    WPack p;
    p.src[0] = gq_w; p.dst[0] = wcat + 0 * 65536; p.K[0] = 256;
    p.src[1] = gk_w; p.dst[1] = wcat + 1 * 65536; p.K[1] = 256;
    p.src[2] = lq_w; p.dst[2] = wcat + 2 * 65536; p.K[2] = 256;
    p.src[3] = lk_w; p.dst[3] = wcat + 3 * 65536; p.K[3] = 256;
    p.src[4] = lv_w; p.dst[4] = wcat + 4 * 65536; p.K[4] = 256;
    p.src[5] = gv_w; p.dst[5] = gv_t;  p.K[5] = 256;
    p.src[6] = go_w; p.dst[6] = goS;   p.K[6] = 256;   // straight
    p.src[7] = f1_w; p.dst[7] = f1_t;  p.K[7] = 512;   // + mirrors K>=256 half into w1cat
    p.src[8] = f2_w; p.dst[8] = f2_t;  p.K[8] = 256;
    p.bsrc[0] = gq_b; p.bsrc[1] = gk_b; p.bsrc[2] = lq_b; p.bsrc[3] = lk_b; p.bsrc[4] = lv_b;
    p.bdst = bcat;
    p.w1cat = w1cat;
    p.f1_b = f1_b; p.go_b = go_b; p.f1_w = f1_w; p.f1bp = f1bp;
    wconv_all<<<dim3(8, 4, 11), 256, 0, stream>>>(p);
    pooled_part<<<256, 256, 0, stream>>>(xb, pp);

    // 1b. W1 = f1A^T @ go_w^T  -> w1cat[:, 0:256]
    gemm_tb<64, 256><<<dim3(4, 2), 256, 0, stream>>>(f1_t, 512, goS, 256, nullptr,
                                                     w1cat, 512, 0, 0, 0, nullptr);

    // 2. fused projection GEMM (q|k|lq|lk|lv) + V^T projection
    gemm_tb<128, 256><<<dim3(BT / 128, 10), 256, 0, stream>>>(xb, 256, wcat, 256, bcat,
                                                              proj, 1280, 0, 0, 0, nullptr);
    gemm_tb<64, 256><<<dim3(4, BT / 128), 256, 0, stream>>>(gv_t, 256, xb, 256, gv_b,
                                                            vT, BT, 0, 0, 1, nullptr);

    // 3. global attention -> fused[:, 0:256] (raw g_out; go folded into W1)
    attn_global2<<<dim3(SEQT / 64, NB * 4), 256, 0, stream>>>(proj, vT, rpb, fused, 512);

    // 4. local attention -> fused[:, 256:512]
    local_attn<<<BT / 4, 256, 0, stream>>>(proj, lk_b, lv_b, fused);

    // 5. FFN (go composed into f1): h = relu(fused @ w1cat^T + f1b')
    gemm_tb<64, 512><<<dim3(BT / 64, 2), 256, 0, stream>>>(fused, 512, w1cat, 512, f1bp,
                                                           hb, 256, 0, 1, 0, nullptr);
    gemm_tb<64, 256><<<dim3(BT / 64, 2), 256, 0, stream>>>(hb, 256, f2_t, 256, f2_b,
                                                           out, 256, 1, 0, 0, x);

    // 6. pattern path
    pattern_k<<<NB, 256, 0, stream>>>(pp, pe, pq_w, pq_b, pk_w, pk_b, out_scores);
}